// Round 3
// baseline (6244.283 us; speedup 1.0000x reference)
//
#include <hip/hip_runtime.h>

// Problem constants
#define Bx    256
#define Tx    512
#define LAT   128
#define CND   32
#define HIDN  512
#define OUTD  64
#define KD    608           // K = 64(prev) + 32(cond) + 512(h)
#define KP    616           // padded LDS/Wg stride in bf16 elems
#define ROWS  32            // batch rows per block
#define NCOLS 32            // gate cols per block (8 units x 4 gates)

typedef unsigned short u16;
typedef unsigned int   u32;
typedef unsigned long long u64;
typedef short s16x8 __attribute__((ext_vector_type(8)));
typedef unsigned short u16x8 __attribute__((ext_vector_type(8)));
typedef unsigned short u16x4 __attribute__((ext_vector_type(4)));
typedef float f32x4 __attribute__((ext_vector_type(4)));

// ws layout (bytes)
#define WG_SLICE (NCOLS * KP * 2)            // 39424 B per hidden slice
#define WG_OFF   0
#define WG_BYTES (64 * WG_SLICE)             // 2523136
#define H0_OFF   (WG_BYTES)                  // h bf16 (fallback path only)
#define H1_OFF   (H0_OFF + Bx * HIDN * 2)
#define CB_OFF   (H1_OFF + Bx * HIDN * 2)    // c0, fp32
#define BS_OFF   (CB_OFF + Bx * HIDN * 4)    // b_ih+b_hh, fp32 [2048]
#define HT_OFF   (BS_OFF + 4 * HIDN * 4)     // tagged h: u64[2][256][256] = 1 MB
#define EP_OFF   (HT_OFF + 2 * Bx * 256 * 8) // epoch u32

// persistent-kernel LDS layout
#define A_BYTES  (ROWS * KP * 2)             // 39424
#define SMEM_SZ  (2 * A_BYTES + HIDN * 4)    // 80896 -> 2 blocks/CU
#define WCHUNK   (A_BYTES / 16)              // 2464 16B chunks per W slice

__device__ __forceinline__ float sigmoidf_(float x) { return 1.0f / (1.0f + __expf(-x)); }

__device__ __forceinline__ u16 f2bf(float f) {          // RNE fp32 -> bf16 bits
    union { float f; u32 u; } v; v.f = f;
    u32 r = (v.u + 0x7FFFu + ((v.u >> 16) & 1u)) >> 16;
    return (u16)r;
}
__device__ __forceinline__ float bf2f(u16 s) {
    union { u32 u; float f; } v; v.u = ((u32)s) << 16;
    return v.f;
}
__device__ __forceinline__ void gl_lds16(const void* g, void* l) {
    __builtin_amdgcn_global_load_lds(
        (const __attribute__((address_space(1))) unsigned int*)g,
        (__attribute__((address_space(3))) unsigned int*)l, 16, 0, 0);
}
// agent-coherent (sc1) accessors: bypass non-coherent per-XCD L2, served at MALL
__device__ __forceinline__ u64 agent_ld64(const u64* p) {
    return __hip_atomic_load(p, __ATOMIC_RELAXED, __HIP_MEMORY_SCOPE_AGENT);
}
__device__ __forceinline__ void agent_st64(u64* p, u64 v) {
    __hip_atomic_store(p, v, __ATOMIC_RELAXED, __HIP_MEMORY_SCOPE_AGENT);
}

// ---------------------------------------------------------------------------
// prep: gather [W_ih | W_hh] -> bf16 Wg[hs][col=g*8+u][k(pad 616)]; bsum;
// bump epoch (graph replays => fresh tag space, stale ht data never matches)
// ---------------------------------------------------------------------------
__global__ __launch_bounds__(256) void prep_w(
    const float* __restrict__ W_ih, const float* __restrict__ W_hh,
    const float* __restrict__ b_ih, const float* __restrict__ b_hh,
    u16* __restrict__ Wg, float* __restrict__ bsum, u32* __restrict__ epoch)
{
    const int idx = blockIdx.x * 256 + threadIdx.x;
    if (idx < 64 * NCOLS * KD) {
        const int k   = idx % KD;
        const int t   = idx / KD;
        const int col = t % NCOLS;
        const int hs  = t / NCOLS;
        const int g = col >> 3, u = col & 7;
        const int n = g * HIDN + hs * 8 + u;
        const float v = (k < 96) ? W_ih[n * 96 + k] : W_hh[n * HIDN + (k - 96)];
        Wg[(hs * NCOLS + col) * KP + k] = f2bf(v);
    }
    if (idx < 4 * HIDN) bsum[idx] = b_ih[idx] + b_hh[idx];
    if (blockIdx.x == 0 && threadIdx.x == 0) *epoch = *epoch + 1u;
}

// ---------------------------------------------------------------------------
// init: h0 = latent @ W_lh^T + b_lh (bf16, plain + tagged); c0 ; out[:,0,:]=1
// ---------------------------------------------------------------------------
__global__ __launch_bounds__(256) void init_kernel(
    const float* __restrict__ latent, const float* __restrict__ W_lh,
    const float* __restrict__ b_lh,   const float* __restrict__ W_lc,
    const float* __restrict__ b_lc,   u16* __restrict__ h0,
    float* __restrict__ c0,           float* __restrict__ out,
    u64* __restrict__ ht,             const u32* __restrict__ epoch)
{
    const int b = blockIdx.x;
    const u32 tag0 = (*epoch) << 9;          // tag of h before step 0
    const float4* lat4 = reinterpret_cast<const float4*>(latent + b * LAT);
    u32 hbits[2];
#pragma unroll
    for (int jj = 0; jj < 2; ++jj) {
        const int j = threadIdx.x + jj * 256;
        const float4* wh4 = reinterpret_cast<const float4*>(W_lh + j * LAT);
        const float4* wc4 = reinterpret_cast<const float4*>(W_lc + j * LAT);
        float sh = 0.f, sc = 0.f;
#pragma unroll 8
        for (int k = 0; k < LAT / 4; ++k) {
            float4 l = lat4[k], a = wh4[k], c = wc4[k];
            sh += l.x * a.x + l.y * a.y + l.z * a.z + l.w * a.w;
            sc += l.x * c.x + l.y * c.y + l.z * c.z + l.w * c.w;
        }
        const u16 hb = f2bf(sh + b_lh[j]);
        hbits[jj] = (u32)hb;
        h0[b * HIDN + j] = hb;
        c0[b * HIDN + j] = sc + b_lc[j];
    }
    // tagged pairs into ht parity 0 (consumed by persist step 0)
    const u32 n0 = (u32)__shfl_xor((int)hbits[0], 1);
    const u32 n1 = (u32)__shfl_xor((int)hbits[1], 1);
    if (!(threadIdx.x & 1)) {
        const int half = threadIdx.x >> 1;
        ht[b * 256 + half]       = (((u64)tag0) << 32) | (hbits[0] | (n0 << 16));
        ht[b * 256 + 128 + half] = (((u64)tag0) << 32) | (hbits[1] | (n1 << 16));
    }
    if (threadIdx.x < OUTD) out[b * (Tx * OUTD) + threadIdx.x] = 1.0f;
}

// ---------------------------------------------------------------------------
// persistent kernel: all 512 steps in one cooperative launch.
// Cross-block h travels as self-validating tagged u64 granules (2 bf16 + tag)
// through agent-scope (sc1) stores/loads: producer fires and forgets (no drain,
// no flag); consumer's load IS the wait (retry stale granules via need-mask).
// ---------------------------------------------------------------------------
__global__ __launch_bounds__(256, 2) void persist_kernel(
    const float* __restrict__ target, const float* __restrict__ cond,
    u64* __restrict__ ht,             const float* __restrict__ cbuf,
    const u16* __restrict__ Wg,       const float* __restrict__ bsum,
    const float* __restrict__ W_out,  const float* __restrict__ b_out,
    float* __restrict__ out,          const u32* __restrict__ epoch)
{
    const int tid  = threadIdx.x;
    const int bs   = blockIdx.x & 7;    // group = batch slice (XCD-local heuristic)
    const int hs   = blockIdx.x >> 3;   // hidden slice 0..63
    const int w    = tid >> 6;
    const int lane = tid & 63;
    const u32 tbase = (*epoch) << 9;

    __shared__ __align__(16) char smem[SMEM_SZ];
    u16*   As   = (u16*)smem;                   // [32][616] activations
    u16*   Ws   = (u16*)(smem + A_BYTES);       // [32][616] weights (persistent)
    float* Wo   = (float*)(smem + 2 * A_BYTES); // [512] W_out col (persistent)
    float* gbuf = (float*)smem;                 // [32][36] alias over As rows 0-3

    // ---- one-time: W slice -> LDS (2464 x 16B chunks)
    {
        const u16* wsrc = Wg + hs * (NCOLS * KP);
#pragma unroll
        for (int it = 0; it < 10; ++it) {
            const int base = it * 256 + w * 64;
            if (base + lane < WCHUNK)
                gl_lds16(wsrc + (base + lane) * 8, (void*)(Ws + base * 8));
        }
    }
    if (tid < 128)
        reinterpret_cast<float4*>(Wo)[tid] =
            reinterpret_cast<const float4*>(W_out + hs * HIDN)[tid];

    const int r_  = tid >> 3, q_ = tid & 7;     // (row, unit) ownership
    const int gb_ = bs * ROWS + r_;
    const int hu_ = hs * 8 + q_;
    float c_reg = cbuf[gb_ * HIDN + hu_];       // c lives in a register forever
    const float bsum0 = bsum[0 * HIDN + hu_];
    const float bsum1 = bsum[1 * HIDN + hu_];
    const float bsum2 = bsum[2 * HIDN + hu_];
    const float bsum3 = bsum[3 * HIDN + hu_];
    const float bo    = b_out[hs];

    u16x4 cond_bf;                              // cond cached in regs
    {
        const float4 cv = *reinterpret_cast<const float4*>(cond + gb_ * CND + q_ * 4);
        cond_bf[0] = f2bf(cv.x); cond_bf[1] = f2bf(cv.y);
        cond_bf[2] = f2bf(cv.z); cond_bf[3] = f2bf(cv.w);
    }

    // MFMA geometry
    const int mrow = ((w & 1) << 4) + (lane & 15);
    const int ncol = ((w >> 1) << 4) + (lane & 15);
    const int kq   = (lane >> 4) << 3;
    const u16* ap  = As + mrow * KP + kq;
    const u16* bp  = Ws + ncol * KP + kq;
    const int row0 = ((w & 1) << 4) + ((lane >> 4) << 2);

    for (int j = 0; j < Tx; ++j) {
        // ---- stage x-part (target prev + cond); As free per loop-end barrier
        if (j < Tx - 1) {
            u16x8 xv;
            if (j == 0) {
#pragma unroll
                for (int m = 0; m < 8; ++m) xv[m] = 0x3F80;  // bf16(1.0)
            } else {
                const float* tg = target + (gb_ * Tx + j) * OUTD + q_ * 8;
                const float4 t0 = *reinterpret_cast<const float4*>(tg);
                const float4 t1 = *reinterpret_cast<const float4*>(tg + 4);
                xv[0]=f2bf(t0.x); xv[1]=f2bf(t0.y); xv[2]=f2bf(t0.z); xv[3]=f2bf(t0.w);
                xv[4]=f2bf(t1.x); xv[5]=f2bf(t1.y); xv[6]=f2bf(t1.z); xv[7]=f2bf(t1.w);
            }
            *reinterpret_cast<u16x8*>(As + r_ * KP + q_ * 8)      = xv;
            *reinterpret_cast<u16x4*>(As + r_ * KP + 64 + q_ * 4) = cond_bf;
        }

        // ---- load+validate h_{j-1}: wait == load (tag carries validity).
        {
            const u64* hp64 = ht + (size_t)(j & 1) * (Bx * 256) + (bs * ROWS) * 256 + tid;
            const u32  texp = tbase + (u32)j;
            u32 need = 0xFFFFFFFFu;
            u64 v[32];
#pragma unroll
            for (int i = 0; i < 32; ++i) v[i] = agent_ld64(hp64 + i * 256);
#pragma unroll
            for (int i = 0; i < 32; ++i) {
                if ((u32)(v[i] >> 32) == texp) {
                    need &= ~(1u << i);
                    *(((u32*)(As + i * KP + 96)) + tid) = (u32)v[i];
                }
            }
            while (!__syncthreads_and((int)(need == 0u))) {
#pragma unroll
                for (int i = 0; i < 32; ++i) {
                    if (need & (1u << i)) {
                        u64 vv = agent_ld64(hp64 + i * 256);
                        if ((u32)(vv >> 32) == texp) {
                            need &= ~(1u << i);
                            *(((u32*)(As + i * KP + 96)) + tid) = (u32)vv;
                        }
                    }
                }
            }
        }   // and-barrier doubles as staging barrier (+ first-iter Ws/Wo drain)

        // ---- output projection out[:, j, hs] from the LDS h copy (j>=1)
        if (j >= 1) {
            const u16*   hrow = As + r_ * KP + 96 + q_ * 64;
            const float* wo   = Wo + q_ * 64;
            float p = 0.f;
#pragma unroll
            for (int i = 0; i < 8; ++i) {
                const int ii = (i + q_) & 7;   // rotate to spread LDS banks
                u16x8 hv  = *reinterpret_cast<const u16x8*>(hrow + ii * 8);
                float4 w0 = *reinterpret_cast<const float4*>(wo + ii * 8);
                float4 w1 = *reinterpret_cast<const float4*>(wo + ii * 8 + 4);
                p += bf2f(hv[0])*w0.x + bf2f(hv[1])*w0.y + bf2f(hv[2])*w0.z + bf2f(hv[3])*w0.w
                   + bf2f(hv[4])*w1.x + bf2f(hv[5])*w1.y + bf2f(hv[6])*w1.z + bf2f(hv[7])*w1.w;
            }
            p += __shfl_xor(p, 1); p += __shfl_xor(p, 2); p += __shfl_xor(p, 4);
            if (q_ == 0) out[gb_ * (Tx * OUTD) + j * OUTD + hs] = p + bo;
        }
        if (j == Tx - 1) break;               // final step: projection only

        // ---- gate GEMM: 4 waves x 16x16 tile, K = 19 chunks of 32
        f32x4 acc = {0.f, 0.f, 0.f, 0.f};
#pragma unroll
        for (int ck = 0; ck < 19; ++ck) {
            s16x8 a = *reinterpret_cast<const s16x8*>(ap + ck * 32);
            s16x8 b = *reinterpret_cast<const s16x8*>(bp + ck * 32);
            acc = __builtin_amdgcn_mfma_f32_16x16x32_bf16(a, b, acc, 0, 0, 0);
        }
        __syncthreads();                      // projection + MFMA reads done
#pragma unroll
        for (int t = 0; t < 4; ++t) gbuf[(row0 + t) * 36 + ncol] = acc[t];
        __syncthreads();

        // ---- cell update (c in register); fire-and-forget tagged h store
        {
            const float gi = gbuf[r_ * 36 +      q_] + bsum0;
            const float gf = gbuf[r_ * 36 +  8 + q_] + bsum1;
            const float gg = gbuf[r_ * 36 + 16 + q_] + bsum2;
            const float go = gbuf[r_ * 36 + 24 + q_] + bsum3;
            const float ig = sigmoidf_(gi), fg = sigmoidf_(gf);
            const float gt = tanhf(gg),     og = sigmoidf_(go);
            c_reg = fg * c_reg + ig * gt;
            const u32 hb = (u32)f2bf(og * tanhf(c_reg));
            const u32 nb = (u32)__shfl_xor((int)hb, 1);   // partner q_^1
            if (!(q_ & 1)) {
                u64* hn = ht + (size_t)((j + 1) & 1) * (Bx * 256);
                agent_st64(hn + gb_ * 256 + (hu_ >> 1),
                           (((u64)(tbase + (u32)(j + 1))) << 32) | (hb | (nb << 16)));
            }
        }
        __syncthreads();   // gbuf reads done before next iter's x-stage writes As
    }
}

// ---------------------------------------------------------------------------
// fallback per-step kernel (verified path, used only if cooperative launch
// is rejected)
// ---------------------------------------------------------------------------
__global__ __launch_bounds__(256, 2) void step_kernel(
    int j,
    const float* __restrict__ target, const float* __restrict__ cond,
    const u16* __restrict__ hprev,    u16* __restrict__ hnext,
    float* __restrict__ cbuf,         const u16* __restrict__ Wg,
    const float* __restrict__ bsum,
    const float* __restrict__ W_out,  const float* __restrict__ b_out,
    float* __restrict__ out)
{
    const int tid  = threadIdx.x;
    const int bs   = blockIdx.x >> 6;
    const int hs   = blockIdx.x & 63;
    const int w    = tid >> 6;
    const int lane = tid & 63;

    if (j >= 1) {
        const int r = tid >> 3, q = tid & 7;
        const int gb = bs * ROWS + r;
        const u16*   hp = hprev + gb * HIDN + q * 64;
        const float* wo = W_out + hs * HIDN + q * 64;
        float p = 0.f;
#pragma unroll
        for (int i = 0; i < 8; ++i) {
            u16x8 hv = *reinterpret_cast<const u16x8*>(hp + i * 8);
            float4 w0 = *reinterpret_cast<const float4*>(wo + i * 8);
            float4 w1 = *reinterpret_cast<const float4*>(wo + i * 8 + 4);
            p += bf2f(hv[0]) * w0.x + bf2f(hv[1]) * w0.y + bf2f(hv[2]) * w0.z + bf2f(hv[3]) * w0.w
               + bf2f(hv[4]) * w1.x + bf2f(hv[5]) * w1.y + bf2f(hv[6]) * w1.z + bf2f(hv[7]) * w1.w;
        }
        p += __shfl_xor(p, 1); p += __shfl_xor(p, 2); p += __shfl_xor(p, 4);
        if (q == 0) out[gb * (Tx * OUTD) + j * OUTD + hs] = p + b_out[hs];
    }
    if (j >= Tx - 1) return;

    __shared__ __align__(16) char smem[2 * ROWS * KP * 2 + 1536];
    u16*   As   = (u16*)smem;
    u16*   Ws   = (u16*)(smem + ROWS * KP * 2);
    float* gbuf = (float*)smem;

    {
        const int r = tid >> 3, t8 = tid & 7;
        const int gb = bs * ROWS + r;
        const float* tg = target + (gb * Tx + j) * OUTD;
#pragma unroll
        for (int m = 0; m < 12; ++m) {
            const int k = t8 * 12 + m;
            float v;
            if (k < OUTD) v = (j == 0) ? 1.0f : tg[k];
            else          v = cond[gb * CND + (k - OUTD)];
            As[r * KP + k] = f2bf(v);
        }
    }
#pragma unroll
    for (int it = 0; it < 8; ++it) {
        const int rr = w + it * 4;
        gl_lds16(hprev + (bs * ROWS + rr) * HIDN + lane * 8, (void*)(As + rr * KP + 96));
    }
    {
        const u16* wsrc = Wg + hs * (NCOLS * KP);
#pragma unroll
        for (int it = 0; it < 10; ++it) {
            const int seg = it * 256 + w * 64;
            gl_lds16(wsrc + seg * 8 + lane * 8, (void*)(Ws + seg * 8));
        }
    }
    __syncthreads();

    const int mrow = ((w & 1) << 4) + (lane & 15);
    const int ncol = ((w >> 1) << 4) + (lane & 15);
    const int kq   = (lane >> 4) << 3;
    const u16* ap = As + mrow * KP + kq;
    const u16* bp = Ws + ncol * KP + kq;
    f32x4 acc = {0.f, 0.f, 0.f, 0.f};
#pragma unroll
    for (int ck = 0; ck < 19; ++ck) {
        s16x8 a = *reinterpret_cast<const s16x8*>(ap + ck * 32);
        s16x8 b = *reinterpret_cast<const s16x8*>(bp + ck * 32);
        acc = __builtin_amdgcn_mfma_f32_16x16x32_bf16(a, b, acc, 0, 0, 0);
    }
    __syncthreads();

    {
        const int row0 = ((w & 1) << 4) + ((lane >> 4) << 2);
#pragma unroll
        for (int t = 0; t < 4; ++t) gbuf[(row0 + t) * 36 + ncol] = acc[t];
    }
    __syncthreads();

    {
        const int r = tid >> 3, u = tid & 7;
        const int gb = bs * ROWS + r, hu = hs * 8 + u;
        const float gi = gbuf[r * 36 +      u] + bsum[0 * HIDN + hu];
        const float gf = gbuf[r * 36 +  8 + u] + bsum[1 * HIDN + hu];
        const float gg = gbuf[r * 36 + 16 + u] + bsum[2 * HIDN + hu];
        const float go = gbuf[r * 36 + 24 + u] + bsum[3 * HIDN + hu];
        const float ig = sigmoidf_(gi), fg = sigmoidf_(gf);
        const float gt = tanhf(gg),     og = sigmoidf_(go);
        const float co = cbuf[gb * HIDN + hu];
        const float cn = fg * co + ig * gt;
        cbuf[gb * HIDN + hu]  = cn;
        hnext[gb * HIDN + hu] = f2bf(og * tanhf(cn));
    }
}

// ---------------------------------------------------------------------------
extern "C" void kernel_launch(void* const* d_in, const int* in_sizes, int n_in,
                              void* d_out, int out_size, void* d_ws, size_t ws_size,
                              hipStream_t stream) {
    const float* latent = (const float*)d_in[0];
    const float* cond   = (const float*)d_in[1];
    const float* target = (const float*)d_in[2];
    const float* W_lh   = (const float*)d_in[3];
    const float* b_lh   = (const float*)d_in[4];
    const float* W_lc   = (const float*)d_in[5];
    const float* b_lc   = (const float*)d_in[6];
    const float* W_ih   = (const float*)d_in[7];
    const float* W_hh   = (const float*)d_in[8];
    const float* b_ih   = (const float*)d_in[9];
    const float* b_hh   = (const float*)d_in[10];
    const float* W_out  = (const float*)d_in[11];
    const float* b_out  = (const float*)d_in[12];

    float* out = (float*)d_out;
    char*  ws  = (char*)d_ws;
    u16*   Wg    = (u16*)(ws + WG_OFF);
    u16*   hbuf0 = (u16*)(ws + H0_OFF);
    u16*   hbuf1 = (u16*)(ws + H1_OFF);
    float* cbuf  = (float*)(ws + CB_OFF);
    float* bsum  = (float*)(ws + BS_OFF);
    u64*   ht    = (u64*)(ws + HT_OFF);
    u32*   epoch = (u32*)(ws + EP_OFF);

    hipLaunchKernelGGL(prep_w, dim3(4864), dim3(256), 0, stream,
                       W_ih, W_hh, b_ih, b_hh, Wg, bsum, epoch);
    hipLaunchKernelGGL(init_kernel, dim3(Bx), dim3(256), 0, stream,
                       latent, W_lh, b_lh, W_lc, b_lc, hbuf0, cbuf, out, ht, epoch);

    {
        const float* t_  = target;  const float* c_  = cond;
        u64*         ht_ = ht;      const float* cb_ = cbuf;
        const u16*   wg_ = Wg;      const float* bs_ = bsum;
        const float* wo_ = W_out;   const float* bo_ = b_out;
        float*       o_  = out;     const u32*   ep_ = epoch;
        void* args[] = { &t_, &c_, &ht_, &cb_, &wg_, &bs_, &wo_, &bo_, &o_, &ep_ };
        hipError_t err = hipLaunchCooperativeKernel(
            reinterpret_cast<const void*>(persist_kernel),
            dim3(512), dim3(256), args, 0, stream);
        if (err != hipSuccess) {
            // fallback: verified per-step launch loop
            for (int j = 0; j < Tx; ++j) {
                u16* hp = (j & 1) ? hbuf1 : hbuf0;
                u16* hn = (j & 1) ? hbuf0 : hbuf1;
                hipLaunchKernelGGL(step_kernel, dim3(512), dim3(256), 0, stream,
                                   j, target, cond, hp, hn, cbuf,
                                   Wg, bsum, W_out, b_out, out);
            }
        }
    }
}

// Round 4
// 2313.842 us; speedup vs baseline: 2.6987x; 2.6987x over previous
//
#include <hip/hip_runtime.h>

// Problem constants
#define Bx    256
#define Tx    512
#define LAT   128
#define CND   32
#define HIDN  512
#define OUTD  64
#define KD    608           // K = 64(prev) + 32(cond) + 512(h)
#define KP    616           // padded LDS/Wg stride in bf16 elems
#define ROWS  32            // batch rows per block
#define NCOLS 32            // gate cols per block (8 units x 4 gates)

typedef unsigned short u16;
typedef unsigned int   u32;
typedef unsigned long long u64;
typedef short s16x8 __attribute__((ext_vector_type(8)));
typedef unsigned short u16x8 __attribute__((ext_vector_type(8)));
typedef unsigned short u16x4 __attribute__((ext_vector_type(4)));
typedef float f32x4 __attribute__((ext_vector_type(4)));

// ws layout (bytes)
#define WG_SLICE (NCOLS * KP * 2)            // 39424 B per hidden slice
#define WG_OFF   0
#define WG_BYTES (64 * WG_SLICE)             // 2523136
#define H0_OFF   (WG_BYTES)                  // h double-buffer, bf16 bits
#define H1_OFF   (H0_OFF + Bx * HIDN * 2)
#define CB_OFF   (H1_OFF + Bx * HIDN * 2)    // c0, fp32
#define BS_OFF   (CB_OFF + Bx * HIDN * 4)    // b_ih+b_hh, fp32 [2048]
#define DN_OFF   (BS_OFF + 4 * HIDN * 4)     // flags u32[8 grp][64 prod][4 wave]

// persistent-kernel LDS layout
#define A_BYTES  (ROWS * KP * 2)             // 39424
#define SMEM_SZ  (2 * A_BYTES + HIDN * 4)    // 80896 -> 2 blocks/CU
#define WCHUNK   (A_BYTES / 16)              // 2464 16B chunks per W slice
#define RB       1232                        // As row stride in bytes (KP*2)

__device__ __forceinline__ float sigmoidf_(float x) { return 1.0f / (1.0f + __expf(-x)); }

__device__ __forceinline__ u16 f2bf(float f) {          // RNE fp32 -> bf16 bits
    union { float f; u32 u; } v; v.f = f;
    u32 r = (v.u + 0x7FFFu + ((v.u >> 16) & 1u)) >> 16;
    return (u16)r;
}
__device__ __forceinline__ float bf2f(u16 s) {
    union { u32 u; float f; } v; v.u = ((u32)s) << 16;
    return v.f;
}
__device__ __forceinline__ void gl_lds16(const void* g, void* l) {
    __builtin_amdgcn_global_load_lds(
        (const __attribute__((address_space(1))) unsigned int*)g,
        (__attribute__((address_space(3))) unsigned int*)l, 16, 0, 0);
}
// agent-coherent (sc1) accessors: bypass non-coherent per-XCD L2 (MALL-served)
__device__ __forceinline__ u32 agent_ld(const u32* p) {
    return __hip_atomic_load(p, __ATOMIC_RELAXED, __HIP_MEMORY_SCOPE_AGENT);
}
__device__ __forceinline__ void agent_st(u32* p, u32 v) {
    __hip_atomic_store(p, v, __ATOMIC_RELAXED, __HIP_MEMORY_SCOPE_AGENT);
}
__device__ __forceinline__ u64 agent_ld64(const u64* p) {
    return __hip_atomic_load(p, __ATOMIC_RELAXED, __HIP_MEMORY_SCOPE_AGENT);
}
__device__ __forceinline__ void agent_st64(u64* p, u64 v) {
    __hip_atomic_store(p, v, __ATOMIC_RELAXED, __HIP_MEMORY_SCOPE_AGENT);
}

// ---------------------------------------------------------------------------
// prep: gather [W_ih | W_hh] -> bf16 Wg[hs][col=g*8+u][k(pad 616)]; bsum; flags=0
// ---------------------------------------------------------------------------
__global__ __launch_bounds__(256) void prep_w(
    const float* __restrict__ W_ih, const float* __restrict__ W_hh,
    const float* __restrict__ b_ih, const float* __restrict__ b_hh,
    u16* __restrict__ Wg, float* __restrict__ bsum, u32* __restrict__ done_arr)
{
    const int idx = blockIdx.x * 256 + threadIdx.x;
    if (idx < 64 * NCOLS * KD) {
        const int k   = idx % KD;
        const int t   = idx / KD;
        const int col = t % NCOLS;
        const int hs  = t / NCOLS;
        const int g = col >> 3, u = col & 7;
        const int n = g * HIDN + hs * 8 + u;
        const float v = (k < 96) ? W_ih[n * 96 + k] : W_hh[n * HIDN + (k - 96)];
        Wg[(hs * NCOLS + col) * KP + k] = f2bf(v);
    }
    if (idx < 4 * HIDN)  bsum[idx] = b_ih[idx] + b_hh[idx];
    if (idx < 8 * 64 * 4) done_arr[idx] = 0u;      // re-zeroed every replay
}

// ---------------------------------------------------------------------------
// init: h0 (bf16) = latent @ W_lh^T + b_lh ; c0 (fp32) ; out[:,0,:] = 1
// ---------------------------------------------------------------------------
__global__ __launch_bounds__(256) void init_kernel(
    const float* __restrict__ latent, const float* __restrict__ W_lh,
    const float* __restrict__ b_lh,   const float* __restrict__ W_lc,
    const float* __restrict__ b_lc,   u16* __restrict__ h0,
    float* __restrict__ c0,           float* __restrict__ out)
{
    const int b = blockIdx.x;
    const float4* lat4 = reinterpret_cast<const float4*>(latent + b * LAT);
#pragma unroll
    for (int jj = 0; jj < 2; ++jj) {
        const int j = threadIdx.x + jj * 256;
        const float4* wh4 = reinterpret_cast<const float4*>(W_lh + j * LAT);
        const float4* wc4 = reinterpret_cast<const float4*>(W_lc + j * LAT);
        float sh = 0.f, sc = 0.f;
#pragma unroll 8
        for (int k = 0; k < LAT / 4; ++k) {
            float4 l = lat4[k], a = wh4[k], c = wc4[k];
            sh += l.x * a.x + l.y * a.y + l.z * a.z + l.w * a.w;
            sc += l.x * c.x + l.y * c.y + l.z * c.z + l.w * c.w;
        }
        h0[b * HIDN + j] = f2bf(sh + b_lh[j]);
        c0[b * HIDN + j] = sc + b_lc[j];
    }
    if (threadIdx.x < OUTD) out[b * (Tx * OUTD) + threadIdx.x] = 1.0f;
}

// ---------------------------------------------------------------------------
// persistent kernel: all 512 steps, one cooperative launch.
// Sync design (r4): per-producer-WAVE flags; consumer thread tid depends on
// exactly one producer wave pair -> polls ONE u64 flag, then loads its own
// 16 u64 h-granules (sc1/MALL). No producer-side barrier before flag (each
// wave drains its own stores). Projection runs after flag publish (reads the
// intact LDS h copy) so its VALU cost overlaps the peers' flag propagation.
// ---------------------------------------------------------------------------
__global__ __launch_bounds__(256, 2) void persist_kernel(
    const float* __restrict__ target, const float* __restrict__ cond,
    u16* __restrict__ hbuf0, u16* __restrict__ hbuf1,
    const float* __restrict__ cbuf, const u16* __restrict__ Wg,
    const float* __restrict__ bsum, const float* __restrict__ W_out,
    const float* __restrict__ b_out, float* __restrict__ out,
    u32* __restrict__ done)
{
    const int tid  = threadIdx.x;
    const int bs   = blockIdx.x & 7;    // group = batch slice (XCD-local heuristic)
    const int hs   = blockIdx.x >> 3;   // hidden slice 0..63
    const int w    = tid >> 6;
    const int lane = tid & 63;

    __shared__ __align__(16) char smem[SMEM_SZ];
    u16*   As = (u16*)smem;                   // [32][616] activations
    u16*   Ws = (u16*)(smem + A_BYTES);       // [32][616] weights (persistent)
    float* Wo = (float*)(smem + 2 * A_BYTES); // [512] W_out col (persistent)
    // gate buffer is remapped into the x-part gap of each As row:
    // gbuf(row, col) = ((float*)(smem + row*RB))[col], col<32 -> bytes<128<192

    // ---- one-time: W slice -> LDS (2464 x 16B chunks)
    {
        const u16* wsrc = Wg + hs * (NCOLS * KP);
#pragma unroll
        for (int it = 0; it < 10; ++it) {
            const int base = it * 256 + w * 64;
            if (base + lane < WCHUNK)
                gl_lds16(wsrc + (base + lane) * 8, (void*)(Ws + base * 8));
        }
    }
    if (tid < 128)
        reinterpret_cast<float4*>(Wo)[tid] =
            reinterpret_cast<const float4*>(W_out + hs * HIDN)[tid];

    const int r_  = tid >> 3, q_ = tid & 7;     // (row, unit) ownership
    const int gb_ = bs * ROWS + r_;
    const int hu_ = hs * 8 + q_;
    float c_reg = cbuf[gb_ * HIDN + hu_];       // c lives in a register forever
    const float bsum0 = bsum[0 * HIDN + hu_];
    const float bsum1 = bsum[1 * HIDN + hu_];
    const float bsum2 = bsum[2 * HIDN + hu_];
    const float bsum3 = bsum[3 * HIDN + hu_];
    const float bo    = b_out[hs];

    u16x4 cond_bf;                              // cond cached in regs
    {
        const float4 cv = *reinterpret_cast<const float4*>(cond + gb_ * CND + q_ * 4);
        cond_bf[0] = f2bf(cv.x); cond_bf[1] = f2bf(cv.y);
        cond_bf[2] = f2bf(cv.z); cond_bf[3] = f2bf(cv.w);
    }

    // consumer h-load mapping: u64 column c2 (0..127) -> producer p=c2>>1;
    // row half rh (16 rows) -> producer waves {2rh, 2rh+1} -> one u64 flag pair
    const int c2 = tid & 127;
    const int rh = tid >> 7;
    const u64* fpp = (const u64*)(done + ((bs * 64 + (c2 >> 1)) << 2) + (rh << 1));

    // MFMA geometry (verified layout)
    const int mrow = ((w & 1) << 4) + (lane & 15);
    const int ncol = ((w >> 1) << 4) + (lane & 15);
    const int kq   = (lane >> 4) << 3;
    const u16* ap  = As + mrow * KP + kq;
    const u16* bp  = Ws + ncol * KP + kq;
    const int row0 = ((w & 1) << 4) + ((lane >> 4) << 2);

    for (int j = 0; j < Tx; ++j) {
        // ---- stage x-part (target prev + cond); As free per loop-end barrier
        if (j < Tx - 1) {
            u16x8 xv;
            if (j == 0) {
#pragma unroll
                for (int m = 0; m < 8; ++m) xv[m] = 0x3F80;  // bf16(1.0)
            } else {
                const float* tg = target + (gb_ * Tx + j) * OUTD + q_ * 8;
                const float4 t0 = *reinterpret_cast<const float4*>(tg);
                const float4 t1 = *reinterpret_cast<const float4*>(tg + 4);
                xv[0]=f2bf(t0.x); xv[1]=f2bf(t0.y); xv[2]=f2bf(t0.z); xv[3]=f2bf(t0.w);
                xv[4]=f2bf(t1.x); xv[5]=f2bf(t1.y); xv[6]=f2bf(t1.z); xv[7]=f2bf(t1.w);
            }
            *reinterpret_cast<u16x8*>(As + r_ * KP + q_ * 8)      = xv;
            *reinterpret_cast<u16x4*>(As + r_ * KP + 64 + q_ * 4) = cond_bf;
        }

        // ---- per-thread wait: one u64 flag pair (this thread's producer waves)
        {
            const u32 jj = (u32)j;
            u64 f = agent_ld64(fpp);
            while ((u32)f < jj || (u32)(f >> 32) < jj) f = agent_ld64(fpp);
        }
        // ---- load this thread's 16 u64 h-granules, write LDS
        {
            const u64* hb = (const u64*)((j & 1) ? hbuf1 : hbuf0);
            const u64* hp = hb + (size_t)(bs * ROWS + rh * 16) * 128 + c2;
            u64 v[16];
#pragma unroll
            for (int m = 0; m < 16; ++m) v[m] = agent_ld64(hp + (size_t)m * 128);
#pragma unroll
            for (int m = 0; m < 16; ++m)
                *reinterpret_cast<u64*>(As + (rh * 16 + m) * KP + 96 + c2 * 4) = v[m];
        }
        __syncthreads();   // all staging done (+ first-iter Ws/Wo drain)

        if (j == Tx - 1) {  // final step: projection only
            const u16*   hrow = As + r_ * KP + 96 + q_ * 64;
            const float* wo   = Wo + q_ * 64;
            float p = 0.f;
#pragma unroll
            for (int i = 0; i < 8; ++i) {
                const int ii = (i + q_) & 7;
                u16x8 hv  = *reinterpret_cast<const u16x8*>(hrow + ii * 8);
                float4 w0 = *reinterpret_cast<const float4*>(wo + ii * 8);
                float4 w1 = *reinterpret_cast<const float4*>(wo + ii * 8 + 4);
                p += bf2f(hv[0])*w0.x + bf2f(hv[1])*w0.y + bf2f(hv[2])*w0.z + bf2f(hv[3])*w0.w
                   + bf2f(hv[4])*w1.x + bf2f(hv[5])*w1.y + bf2f(hv[6])*w1.z + bf2f(hv[7])*w1.w;
            }
            p += __shfl_xor(p, 1); p += __shfl_xor(p, 2); p += __shfl_xor(p, 4);
            if (q_ == 0) out[gb_ * (Tx * OUTD) + j * OUTD + hs] = p + bo;
            break;
        }

        // ---- gate GEMM: 4 waves x 16x16 tile, K = 19 chunks of 32
        f32x4 acc = {0.f, 0.f, 0.f, 0.f};
#pragma unroll
        for (int ck = 0; ck < 19; ++ck) {
            s16x8 a = *reinterpret_cast<const s16x8*>(ap + ck * 32);
            s16x8 b = *reinterpret_cast<const s16x8*>(bp + ck * 32);
            acc = __builtin_amdgcn_mfma_f32_16x16x32_bf16(a, b, acc, 0, 0, 0);
        }
        __syncthreads();                      // all MFMA LDS reads done
        // ---- scatter gates into per-row x-part gaps (h-part stays intact)
#pragma unroll
        for (int t = 0; t < 4; ++t)
            reinterpret_cast<float*>(smem + (size_t)(row0 + t) * RB)[ncol] = acc[t];
        __syncthreads();

        // ---- cell update (c in register); packed u64 h store; per-wave flag
        {
            const float* gr = reinterpret_cast<const float*>(smem + (size_t)r_ * RB);
            const float gi = gr[     q_] + bsum0;
            const float gf = gr[ 8 + q_] + bsum1;
            const float gg = gr[16 + q_] + bsum2;
            const float go = gr[24 + q_] + bsum3;
            const float ig = sigmoidf_(gi), fg = sigmoidf_(gf);
            const float gt = tanhf(gg),     og = sigmoidf_(go);
            c_reg = fg * c_reg + ig * gt;
            const u32 hbit = (u32)f2bf(og * tanhf(c_reg));
            const u32 pair = hbit | ((u32)__shfl_xor((int)hbit, 1) << 16);   // even q
            const u64 quad = (u64)pair |
                             ((u64)(u32)__shfl_xor((int)pair, 2) << 32);     // q%4==0
            if ((q_ & 3) == 0) {
                u64* hn = (u64*)((j & 1) ? hbuf0 : hbuf1);
                agent_st64(hn + (size_t)gb_ * 128 + hs * 2 + (q_ >> 2), quad);
            }
        }
        // wave-local drain of the sc1 stores, then this wave's flag (no barrier)
        asm volatile("s_waitcnt vmcnt(0)" ::: "memory");
        if (lane == 0)
            agent_st(done + ((bs * 64 + hs) << 2) + w, (u32)(j + 1));

        // ---- projection out[:, j, hs] (j>=1): off the critical path — overlaps
        // the peers' flag propagation; reads the intact LDS h-part.
        if (j >= 1) {
            const u16*   hrow = As + r_ * KP + 96 + q_ * 64;
            const float* wo   = Wo + q_ * 64;
            float p = 0.f;
#pragma unroll
            for (int i = 0; i < 8; ++i) {
                const int ii = (i + q_) & 7;
                u16x8 hv  = *reinterpret_cast<const u16x8*>(hrow + ii * 8);
                float4 w0 = *reinterpret_cast<const float4*>(wo + ii * 8);
                float4 w1 = *reinterpret_cast<const float4*>(wo + ii * 8 + 4);
                p += bf2f(hv[0])*w0.x + bf2f(hv[1])*w0.y + bf2f(hv[2])*w0.z + bf2f(hv[3])*w0.w
                   + bf2f(hv[4])*w1.x + bf2f(hv[5])*w1.y + bf2f(hv[6])*w1.z + bf2f(hv[7])*w1.w;
            }
            p += __shfl_xor(p, 1); p += __shfl_xor(p, 2); p += __shfl_xor(p, 4);
            if (q_ == 0) out[gb_ * (Tx * OUTD) + j * OUTD + hs] = p + bo;
        }
        __syncthreads();   // As/gbuf reads done before next iter's x-stage writes
    }
}

// ---------------------------------------------------------------------------
// fallback per-step kernel (verified path, used only if cooperative launch
// is rejected)
// ---------------------------------------------------------------------------
__global__ __launch_bounds__(256, 2) void step_kernel(
    int j,
    const float* __restrict__ target, const float* __restrict__ cond,
    const u16* __restrict__ hprev,    u16* __restrict__ hnext,
    float* __restrict__ cbuf,         const u16* __restrict__ Wg,
    const float* __restrict__ bsum,
    const float* __restrict__ W_out,  const float* __restrict__ b_out,
    float* __restrict__ out)
{
    const int tid  = threadIdx.x;
    const int bs   = blockIdx.x >> 6;
    const int hs   = blockIdx.x & 63;
    const int w    = tid >> 6;
    const int lane = tid & 63;

    if (j >= 1) {
        const int r = tid >> 3, q = tid & 7;
        const int gb = bs * ROWS + r;
        const u16*   hp = hprev + gb * HIDN + q * 64;
        const float* wo = W_out + hs * HIDN + q * 64;
        float p = 0.f;
#pragma unroll
        for (int i = 0; i < 8; ++i) {
            u16x8 hv = *reinterpret_cast<const u16x8*>(hp + i * 8);
            float4 w0 = *reinterpret_cast<const float4*>(wo + i * 8);
            float4 w1 = *reinterpret_cast<const float4*>(wo + i * 8 + 4);
            p += bf2f(hv[0]) * w0.x + bf2f(hv[1]) * w0.y + bf2f(hv[2]) * w0.z + bf2f(hv[3]) * w0.w
               + bf2f(hv[4]) * w1.x + bf2f(hv[5]) * w1.y + bf2f(hv[6]) * w1.z + bf2f(hv[7]) * w1.w;
        }
        p += __shfl_xor(p, 1); p += __shfl_xor(p, 2); p += __shfl_xor(p, 4);
        if (q == 0) out[gb * (Tx * OUTD) + j * OUTD + hs] = p + b_out[hs];
    }
    if (j >= Tx - 1) return;

    __shared__ __align__(16) char smem[2 * ROWS * KP * 2 + 1536];
    u16*   As   = (u16*)smem;
    u16*   Ws   = (u16*)(smem + ROWS * KP * 2);
    float* gbuf = (float*)smem;

    {
        const int r = tid >> 3, t8 = tid & 7;
        const int gb = bs * ROWS + r;
        const float* tg = target + (gb * Tx + j) * OUTD;
#pragma unroll
        for (int m = 0; m < 12; ++m) {
            const int k = t8 * 12 + m;
            float v;
            if (k < OUTD) v = (j == 0) ? 1.0f : tg[k];
            else          v = cond[gb * CND + (k - OUTD)];
            As[r * KP + k] = f2bf(v);
        }
    }
#pragma unroll
    for (int it = 0; it < 8; ++it) {
        const int rr = w + it * 4;
        gl_lds16(hprev + (bs * ROWS + rr) * HIDN + lane * 8, (void*)(As + rr * KP + 96));
    }
    {
        const u16* wsrc = Wg + hs * (NCOLS * KP);
#pragma unroll
        for (int it = 0; it < 10; ++it) {
            const int seg = it * 256 + w * 64;
            gl_lds16(wsrc + seg * 8 + lane * 8, (void*)(Ws + seg * 8));
        }
    }
    __syncthreads();

    const int mrow = ((w & 1) << 4) + (lane & 15);
    const int ncol = ((w >> 1) << 4) + (lane & 15);
    const int kq   = (lane >> 4) << 3;
    const u16* ap = As + mrow * KP + kq;
    const u16* bp = Ws + ncol * KP + kq;
    f32x4 acc = {0.f, 0.f, 0.f, 0.f};
#pragma unroll
    for (int ck = 0; ck < 19; ++ck) {
        s16x8 a = *reinterpret_cast<const s16x8*>(ap + ck * 32);
        s16x8 b = *reinterpret_cast<const s16x8*>(bp + ck * 32);
        acc = __builtin_amdgcn_mfma_f32_16x16x32_bf16(a, b, acc, 0, 0, 0);
    }
    __syncthreads();

    {
        const int row0 = ((w & 1) << 4) + ((lane >> 4) << 2);
#pragma unroll
        for (int t = 0; t < 4; ++t) gbuf[(row0 + t) * 36 + ncol] = acc[t];
    }
    __syncthreads();

    {
        const int r = tid >> 3, u = tid & 7;
        const int gb = bs * ROWS + r, hu = hs * 8 + u;
        const float gi = gbuf[r * 36 +      u] + bsum[0 * HIDN + hu];
        const float gf = gbuf[r * 36 +  8 + u] + bsum[1 * HIDN + hu];
        const float gg = gbuf[r * 36 + 16 + u] + bsum[2 * HIDN + hu];
        const float go = gbuf[r * 36 + 24 + u] + bsum[3 * HIDN + hu];
        const float ig = sigmoidf_(gi), fg = sigmoidf_(gf);
        const float gt = tanhf(gg),     og = sigmoidf_(go);
        const float co = cbuf[gb * HIDN + hu];
        const float cn = fg * co + ig * gt;
        cbuf[gb * HIDN + hu]  = cn;
        hnext[gb * HIDN + hu] = f2bf(og * tanhf(cn));
    }
}

// ---------------------------------------------------------------------------
extern "C" void kernel_launch(void* const* d_in, const int* in_sizes, int n_in,
                              void* d_out, int out_size, void* d_ws, size_t ws_size,
                              hipStream_t stream) {
    const float* latent = (const float*)d_in[0];
    const float* cond   = (const float*)d_in[1];
    const float* target = (const float*)d_in[2];
    const float* W_lh   = (const float*)d_in[3];
    const float* b_lh   = (const float*)d_in[4];
    const float* W_lc   = (const float*)d_in[5];
    const float* b_lc   = (const float*)d_in[6];
    const float* W_ih   = (const float*)d_in[7];
    const float* W_hh   = (const float*)d_in[8];
    const float* b_ih   = (const float*)d_in[9];
    const float* b_hh   = (const float*)d_in[10];
    const float* W_out  = (const float*)d_in[11];
    const float* b_out  = (const float*)d_in[12];

    float* out = (float*)d_out;
    char*  ws  = (char*)d_ws;
    u16*   Wg    = (u16*)(ws + WG_OFF);
    u16*   hbuf0 = (u16*)(ws + H0_OFF);
    u16*   hbuf1 = (u16*)(ws + H1_OFF);
    float* cbuf  = (float*)(ws + CB_OFF);
    float* bsum  = (float*)(ws + BS_OFF);
    u32*   done  = (u32*)(ws + DN_OFF);

    hipLaunchKernelGGL(prep_w, dim3(4864), dim3(256), 0, stream,
                       W_ih, W_hh, b_ih, b_hh, Wg, bsum, done);
    hipLaunchKernelGGL(init_kernel, dim3(Bx), dim3(256), 0, stream,
                       latent, W_lh, b_lh, W_lc, b_lc, hbuf0, cbuf, out);

    {
        const float* t_  = target;  const float* c_  = cond;
        u16*         h0_ = hbuf0;   u16*         h1_ = hbuf1;
        const float* cb_ = cbuf;    const u16*   wg_ = Wg;
        const float* bs_ = bsum;    const float* wo_ = W_out;
        const float* bo_ = b_out;   float*       o_  = out;
        u32*         dn_ = done;
        void* args[] = { &t_, &c_, &h0_, &h1_, &cb_, &wg_, &bs_, &wo_, &bo_, &o_, &dn_ };
        hipError_t err = hipLaunchCooperativeKernel(
            reinterpret_cast<const void*>(persist_kernel),
            dim3(512), dim3(256), args, 0, stream);
        if (err != hipSuccess) {
            // fallback: verified per-step launch loop
            for (int j = 0; j < Tx; ++j) {
                u16* hp = (j & 1) ? hbuf1 : hbuf0;
                u16* hn = (j & 1) ? hbuf0 : hbuf1;
                hipLaunchKernelGGL(step_kernel, dim3(512), dim3(256), 0, stream,
                                   j, target, cond, hp, hn, cbuf,
                                   Wg, bsum, W_out, b_out, out);
            }
        }
    }
}

// Round 7
// 2254.938 us; speedup vs baseline: 2.7692x; 1.0261x over previous
//
#include <hip/hip_runtime.h>

// Problem constants
#define Bx    256
#define Tx    512
#define LAT   128
#define CND   32
#define HIDN  512
#define OUTD  64
#define KD    608           // K = 64(prev) + 32(cond) + 512(h)
#define KP    616           // padded LDS/Wg stride in bf16 elems
#define ROWS  32            // batch rows per block
#define NCOLS 32            // fallback kernel: gate cols per block (8 units x 4 gates)

typedef unsigned short u16;
typedef unsigned int   u32;
typedef unsigned long long u64;
typedef short s16x8 __attribute__((ext_vector_type(8)));
typedef unsigned short u16x8 __attribute__((ext_vector_type(8)));
typedef unsigned short u16x4 __attribute__((ext_vector_type(4)));
typedef float f32x4 __attribute__((ext_vector_type(4)));

// ws layout (bytes)
#define WG_BYTES (2048 * KP * 2)             // 2523136 (both layouts same size)
#define WG_OFF   0                            // NEW layout: [hs32][col64][KP]
#define WG2_OFF  (WG_BYTES)                   // OLD layout: [hs64][col32][KP] (fallback)
#define H0_OFF   (WG2_OFF + WG_BYTES)         // h double-buffer, bf16 bits
#define H1_OFF   (H0_OFF + Bx * HIDN * 2)
#define CB_OFF   (H1_OFF + Bx * HIDN * 2)     // c0, fp32
#define BS_OFF   (CB_OFF + Bx * HIDN * 4)     // b_ih+b_hh, fp32 [2048]
#define DN_OFF   (BS_OFF + 4 * HIDN * 4)      // flags u32[8 grp][32 prod][4 wave]

// persistent-kernel dynamic LDS layout (1 block/CU)
#define PA_BYTES 39424                        // As [32][616] bf16
#define PW_BYTES 78848                        // Ws [64][616] bf16
#define PO_BYTES 4096                         // Wo [2][512] f32
#define PG_BYTES 8704                         // gbuf [32][68] f32
#define PSMEM    (PA_BYTES + PW_BYTES + PO_BYTES + PG_BYTES)   // 131072

__device__ __forceinline__ float sigmoidf_(float x) { return 1.0f / (1.0f + __expf(-x)); }

__device__ __forceinline__ u16 f2bf(float f) {          // RNE fp32 -> bf16 bits
    union { float f; u32 u; } v; v.f = f;
    u32 r = (v.u + 0x7FFFu + ((v.u >> 16) & 1u)) >> 16;
    return (u16)r;
}
__device__ __forceinline__ float bf2f(u16 s) {
    union { u32 u; float f; } v; v.u = ((u32)s) << 16;
    return v.f;
}
__device__ __forceinline__ void gl_lds16(const void* g, void* l) {
    __builtin_amdgcn_global_load_lds(
        (const __attribute__((address_space(1))) unsigned int*)g,
        (__attribute__((address_space(3))) unsigned int*)l, 16, 0, 0);
}
// agent-coherent (sc1) accessors: MALL-served, cross-XCD safe (r2/r4-verified)
__device__ __forceinline__ u32 agent_ld(const u32* p) {
    return __hip_atomic_load(p, __ATOMIC_RELAXED, __HIP_MEMORY_SCOPE_AGENT);
}
__device__ __forceinline__ void agent_st(u32* p, u32 v) {
    __hip_atomic_store(p, v, __ATOMIC_RELAXED, __HIP_MEMORY_SCOPE_AGENT);
}
__device__ __forceinline__ u64 agent_ld64(const u64* p) {
    return __hip_atomic_load(p, __ATOMIC_RELAXED, __HIP_MEMORY_SCOPE_AGENT);
}
__device__ __forceinline__ void agent_st64(u64* p, u64 v) {
    __hip_atomic_store(p, v, __ATOMIC_RELAXED, __HIP_MEMORY_SCOPE_AGENT);
}

// ---------------------------------------------------------------------------
// prep: gather [W_ih | W_hh] into BOTH layouts (new for persist, old for
// fallback); bsum = b_ih+b_hh; zero flags (every replay)
// ---------------------------------------------------------------------------
__global__ __launch_bounds__(256) void prep_w(
    const float* __restrict__ W_ih, const float* __restrict__ W_hh,
    const float* __restrict__ b_ih, const float* __restrict__ b_hh,
    u16* __restrict__ Wg, u16* __restrict__ Wg2,
    float* __restrict__ bsum, u32* __restrict__ done_arr)
{
    const int idx = blockIdx.x * 256 + threadIdx.x;
    if (idx < 2048 * KD) {
        const int k   = idx % KD;
        const int t   = idx / KD;      // 0..2047
        const int col = t & 63;        // new layout: col = g*16 + u
        const int hs  = t >> 6;        // 0..31
        const int g = col >> 4, u = col & 15;
        const int n = g * HIDN + hs * 16 + u;
        const float v = (k < 96) ? W_ih[n * 96 + k] : W_hh[n * HIDN + (k - 96)];
        const u16 b = f2bf(v);
        Wg[(hs * 64 + col) * KP + k] = b;
        // old layout (fallback step_kernel): hsO=(n&511)>>3, colO=g*8+(n&7)
        const int nn = n & 511;
        Wg2[(((nn >> 3) * 32) + g * 8 + (nn & 7)) * KP + k] = b;
    }
    if (idx < 4 * HIDN)   bsum[idx] = b_ih[idx] + b_hh[idx];
    if (idx < 8 * 32 * 4) done_arr[idx] = 0u;
}

// ---------------------------------------------------------------------------
// init: h0 (bf16) = latent @ W_lh^T + b_lh ; c0 (fp32) ; out[:,0,:] = 1
// ---------------------------------------------------------------------------
__global__ __launch_bounds__(256) void init_kernel(
    const float* __restrict__ latent, const float* __restrict__ W_lh,
    const float* __restrict__ b_lh,   const float* __restrict__ W_lc,
    const float* __restrict__ b_lc,   u16* __restrict__ h0,
    float* __restrict__ c0,           float* __restrict__ out)
{
    const int b = blockIdx.x;
    const float4* lat4 = reinterpret_cast<const float4*>(latent + b * LAT);
#pragma unroll
    for (int jj = 0; jj < 2; ++jj) {
        const int j = threadIdx.x + jj * 256;
        const float4* wh4 = reinterpret_cast<const float4*>(W_lh + j * LAT);
        const float4* wc4 = reinterpret_cast<const float4*>(W_lc + j * LAT);
        float sh = 0.f, sc = 0.f;
#pragma unroll 8
        for (int k = 0; k < LAT / 4; ++k) {
            float4 l = lat4[k], a = wh4[k], c = wc4[k];
            sh += l.x * a.x + l.y * a.y + l.z * a.z + l.w * a.w;
            sc += l.x * c.x + l.y * c.y + l.z * c.z + l.w * c.w;
        }
        h0[b * HIDN + j] = f2bf(sh + b_lh[j]);
        c0[b * HIDN + j] = sc + b_lc[j];
    }
    if (threadIdx.x < OUTD) out[b * (Tx * OUTD) + threadIdx.x] = 1.0f;
}

// ---------------------------------------------------------------------------
// persistent kernel, r7: 256 blocks = 8 batch groups x 32 hidden slices
// (32 rows x 16 units per block; NCOLS=64 gate cols; 1 block/CU; 128 KB LDS).
// Halves the MALL h-broadcast (32 consumers per panel instead of 64) and
// halves poll traffic. Sync protocol identical to verified r4: per-producer-
// WAVE monotonic sc1 flags, per-thread single u64-flag-pair wait.
// ---------------------------------------------------------------------------
__global__ __launch_bounds__(256, 1) void persist_kernel(
    const float* __restrict__ target, const float* __restrict__ cond,
    u16* __restrict__ hbuf0, u16* __restrict__ hbuf1,
    const float* __restrict__ cbuf, const u16* __restrict__ Wg,
    const float* __restrict__ bsum, const float* __restrict__ W_out,
    const float* __restrict__ b_out, float* __restrict__ out,
    u32* __restrict__ done)
{
    const int tid  = threadIdx.x;
    const int bs   = blockIdx.x & 7;    // batch group (XCD-locality heuristic only)
    const int hs   = blockIdx.x >> 3;   // hidden slice 0..31 (16 units)
    const int w    = tid >> 6;
    const int lane = tid & 63;

    extern __shared__ __align__(16) char smem[];
    u16*   As   = (u16*)smem;                               // [32][616]
    u16*   Ws   = (u16*)(smem + PA_BYTES);                  // [64][616]
    float* Wo   = (float*)(smem + PA_BYTES + PW_BYTES);     // [2][512]
    float* gbuf = (float*)(smem + PA_BYTES + PW_BYTES + PO_BYTES); // [32][68]

    // ---- one-time: W slice -> LDS (4928 x 16B chunks)
    {
        const u16* wsrc = Wg + hs * (64 * KP);
#pragma unroll
        for (int it = 0; it < 20; ++it) {
            const int c = it * 256 + tid;
            if (c < PW_BYTES / 16) gl_lds16(wsrc + c * 8, (void*)(Ws + c * 8));
        }
    }
    // W_out rows 2hs, 2hs+1 (contiguous 1024 floats)
    reinterpret_cast<float4*>(Wo)[tid] =
        reinterpret_cast<const float4*>(W_out + (hs * 2) * HIDN)[tid];

    // cell ownership: thread = (row pair rr, unit u_)
    const int u_   = tid & 15;          // unit 0..15
    const int rr   = tid >> 4;          // 0..15 -> rows 2rr, 2rr+1 (wave w: rows 8w..8w+7)
    const int row0c = 2 * rr, row1c = 2 * rr + 1;
    const int gbr0 = bs * ROWS + row0c;
    const int hu_  = hs * 16 + u_;
    float c0r = cbuf[gbr0 * HIDN + hu_];
    float c1r = cbuf[(gbr0 + 1) * HIDN + hu_];
    const float bsm0 = bsum[0 * HIDN + hu_];
    const float bsm1 = bsum[1 * HIDN + hu_];
    const float bsm2 = bsum[2 * HIDN + hu_];
    const float bsm3 = bsum[3 * HIDN + hu_];

    // x-stage / projection ownership: thread = (row r_, strip q_)
    const int r_ = tid >> 3, q_ = tid & 7;
    const int gb_ = bs * ROWS + r_;
    const float bo0 = b_out[hs * 2], bo1 = b_out[hs * 2 + 1];

    u16x4 cond_bf;                              // cond cached in regs
    {
        const float4 cv = *reinterpret_cast<const float4*>(cond + gb_ * CND + q_ * 4);
        cond_bf[0] = f2bf(cv.x); cond_bf[1] = f2bf(cv.y);
        cond_bf[2] = f2bf(cv.z); cond_bf[3] = f2bf(cv.w);
    }

    // consumer h mapping: u64 col c2 (0..127) = units 4c2..4c2+3 -> producer
    // c2>>2; row half rh -> producer waves {2rh,2rh+1} -> one u64 flag pair
    const int c2 = tid & 127;
    const int rh = tid >> 7;
    const u64* fpp = (const u64*)(done + ((bs * 32 + (c2 >> 2)) << 2) + (rh << 1));

    // MFMA geometry: wave w -> N-tile w (cols w*16..+16), both M-tiles
    const int ml   = lane & 15;
    const int ncol = w * 16 + ml;
    const int kq   = (lane >> 4) << 3;
    const u16* ap0 = As + ml * KP + kq;
    const u16* ap1 = As + (16 + ml) * KP + kq;
    const u16* bp  = Ws + ncol * KP + kq;
    const int  sr0 = (lane >> 4) << 2;   // scatter row base (tile0)

    for (int j = 0; j < Tx; ++j) {
        // ---- stage x-part (target prev + cond); As free per loop-end barrier
        if (j < Tx - 1) {
            u16x8 xv;
            if (j == 0) {
#pragma unroll
                for (int m = 0; m < 8; ++m) xv[m] = 0x3F80;  // bf16(1.0)
            } else {
                const float* tg = target + (gb_ * Tx + j) * OUTD + q_ * 8;
                const float4 t0 = *reinterpret_cast<const float4*>(tg);
                const float4 t1 = *reinterpret_cast<const float4*>(tg + 4);
                xv[0]=f2bf(t0.x); xv[1]=f2bf(t0.y); xv[2]=f2bf(t0.z); xv[3]=f2bf(t0.w);
                xv[4]=f2bf(t1.x); xv[5]=f2bf(t1.y); xv[6]=f2bf(t1.z); xv[7]=f2bf(t1.w);
            }
            *reinterpret_cast<u16x8*>(As + r_ * KP + q_ * 8)      = xv;
            *reinterpret_cast<u16x4*>(As + r_ * KP + 64 + q_ * 4) = cond_bf;
        }

        // ---- per-thread wait: one u64 flag pair (this thread's producer waves)
        if (j > 0) {
            const u32 jj = (u32)j;
            u64 f = agent_ld64(fpp);
            while ((u32)f < jj || (u32)(f >> 32) < jj) f = agent_ld64(fpp);
        }
        // ---- load this thread's 16 u64 h-granules, write LDS
        {
            const u64* hb = (const u64*)((j & 1) ? hbuf1 : hbuf0);
            const u64* hp = hb + (size_t)(bs * ROWS + rh * 16) * 128 + c2;
            u64 v[16];
#pragma unroll
            for (int m = 0; m < 16; ++m) v[m] = agent_ld64(hp + (size_t)m * 128);
#pragma unroll
            for (int m = 0; m < 16; ++m)
                *reinterpret_cast<u64*>(As + (rh * 16 + m) * KP + 96 + c2 * 4) = v[m];
        }
        __syncthreads();   // all staging done (+ first-iter Ws/Wo drain)

        if (j == Tx - 1) {  // final step: projection only (both out cols)
            const u16* hrow = As + r_ * KP + 96 + q_ * 64;
            float p0 = 0.f, p1 = 0.f;
#pragma unroll
            for (int i = 0; i < 8; ++i) {
                const int ii = (i + q_) & 7;
                u16x8 hv = *reinterpret_cast<const u16x8*>(hrow + ii * 8);
                const float* wo0 = Wo + q_ * 64 + ii * 8;
                const float* wo1 = Wo + 512 + q_ * 64 + ii * 8;
#pragma unroll
                for (int m = 0; m < 8; ++m) {
                    const float hf = bf2f(hv[m]);
                    p0 += hf * wo0[m]; p1 += hf * wo1[m];
                }
            }
            p0 += __shfl_xor(p0, 1); p0 += __shfl_xor(p0, 2); p0 += __shfl_xor(p0, 4);
            p1 += __shfl_xor(p1, 1); p1 += __shfl_xor(p1, 2); p1 += __shfl_xor(p1, 4);
            if (q_ == 0) {
                float* op = out + gb_ * (Tx * OUTD) + j * OUTD + hs * 2;
                op[0] = p0 + bo0; op[1] = p1 + bo1;
            }
            break;
        }

        // ---- gate GEMM: 4 waves x (2 M-tiles x 1 N-tile), K = 19 chunks of 32
        f32x4 acc0 = {0.f, 0.f, 0.f, 0.f};
        f32x4 acc1 = {0.f, 0.f, 0.f, 0.f};
#pragma unroll
        for (int ck = 0; ck < 19; ++ck) {
            s16x8 a0 = *reinterpret_cast<const s16x8*>(ap0 + ck * 32);
            s16x8 a1 = *reinterpret_cast<const s16x8*>(ap1 + ck * 32);
            s16x8 b  = *reinterpret_cast<const s16x8*>(bp  + ck * 32);
            acc0 = __builtin_amdgcn_mfma_f32_16x16x32_bf16(a0, b, acc0, 0, 0, 0);
            acc1 = __builtin_amdgcn_mfma_f32_16x16x32_bf16(a1, b, acc1, 0, 0, 0);
        }
        // gbuf is disjoint from As -> no barrier needed before scatter
#pragma unroll
        for (int t = 0; t < 4; ++t) {
            gbuf[(sr0 + t) * 68 + ncol]        = acc0[t];
            gbuf[(sr0 + t + 16) * 68 + ncol]   = acc1[t];
        }
        __syncthreads();

        // ---- cell update x2 rows (c in registers); packed u64 h stores
        {
            const float gi0 = gbuf[row0c * 68 +      u_] + bsm0;
            const float gf0 = gbuf[row0c * 68 + 16 + u_] + bsm1;
            const float gg0 = gbuf[row0c * 68 + 32 + u_] + bsm2;
            const float go0 = gbuf[row0c * 68 + 48 + u_] + bsm3;
            const float gi1 = gbuf[row1c * 68 +      u_] + bsm0;
            const float gf1 = gbuf[row1c * 68 + 16 + u_] + bsm1;
            const float gg1 = gbuf[row1c * 68 + 32 + u_] + bsm2;
            const float go1 = gbuf[row1c * 68 + 48 + u_] + bsm3;
            c0r = sigmoidf_(gf0) * c0r + sigmoidf_(gi0) * tanhf(gg0);
            c1r = sigmoidf_(gf1) * c1r + sigmoidf_(gi1) * tanhf(gg1);
            const u32 h0b = (u32)f2bf(sigmoidf_(go0) * tanhf(c0r));
            const u32 h1b = (u32)f2bf(sigmoidf_(go1) * tanhf(c1r));
            // lane = (rr&3)*16 + u_  ->  xor1/xor2 pair units u_^1, u_^2
            const u32 p0 = h0b | ((u32)__shfl_xor((int)h0b, 1) << 16);
            const u32 p1 = h1b | ((u32)__shfl_xor((int)h1b, 1) << 16);
            const u64 q0 = (u64)p0 | ((u64)(u32)__shfl_xor((int)p0, 2) << 32);
            const u64 q1 = (u64)p1 | ((u64)(u32)__shfl_xor((int)p1, 2) << 32);
            if ((u_ & 3) == 0) {
                u64* hn = (u64*)((j & 1) ? hbuf0 : hbuf1);
                u64* a = hn + (size_t)gbr0 * 128 + hs * 4 + (u_ >> 2);
                agent_st64(a, q0);
                agent_st64(a + 128, q1);   // row 2rr+1
            }
        }
        // wave-local drain of h stores, then this wave's flag (no barrier)
        asm volatile("s_waitcnt vmcnt(0)" ::: "memory");
        if (lane == 0)
            agent_st(done + ((bs * 32 + hs) << 2) + w, (u32)(j + 1));

        // ---- projection (j>=1): off critical path, overlaps flag propagation
        if (j >= 1) {
            const u16* hrow = As + r_ * KP + 96 + q_ * 64;
            float p0 = 0.f, p1 = 0.f;
#pragma unroll
            for (int i = 0; i < 8; ++i) {
                const int ii = (i + q_) & 7;
                u16x8 hv = *reinterpret_cast<const u16x8*>(hrow + ii * 8);
                const float* wo0 = Wo + q_ * 64 + ii * 8;
                const float* wo1 = Wo + 512 + q_ * 64 + ii * 8;
#pragma unroll
                for (int m = 0; m < 8; ++m) {
                    const float hf = bf2f(hv[m]);
                    p0 += hf * wo0[m]; p1 += hf * wo1[m];
                }
            }
            p0 += __shfl_xor(p0, 1); p0 += __shfl_xor(p0, 2); p0 += __shfl_xor(p0, 4);
            p1 += __shfl_xor(p1, 1); p1 += __shfl_xor(p1, 2); p1 += __shfl_xor(p1, 4);
            if (q_ == 0) {
                float* op = out + gb_ * (Tx * OUTD) + j * OUTD + hs * 2;
                op[0] = p0 + bo0; op[1] = p1 + bo1;
            }
        }
        __syncthreads();   // As/gbuf reads done before next iter's writes
    }
}

// ---------------------------------------------------------------------------
// fallback per-step kernel (r4-verified path; uses OLD Wg2 layout). Used only
// if the cooperative launch is rejected.
// ---------------------------------------------------------------------------
__global__ __launch_bounds__(256, 2) void step_kernel(
    int j,
    const float* __restrict__ target, const float* __restrict__ cond,
    const u16* __restrict__ hprev,    u16* __restrict__ hnext,
    float* __restrict__ cbuf,         const u16* __restrict__ Wg,
    const float* __restrict__ bsum,
    const float* __restrict__ W_out,  const float* __restrict__ b_out,
    float* __restrict__ out)
{
    const int tid  = threadIdx.x;
    const int bs   = blockIdx.x >> 6;
    const int hs   = blockIdx.x & 63;
    const int w    = tid >> 6;
    const int lane = tid & 63;

    if (j >= 1) {
        const int r = tid >> 3, q = tid & 7;
        const int gb = bs * ROWS + r;
        const u16*   hp = hprev + gb * HIDN + q * 64;
        const float* wo = W_out + hs * HIDN + q * 64;
        float p = 0.f;
#pragma unroll
        for (int i = 0; i < 8; ++i) {
            u16x8 hv = *reinterpret_cast<const u16x8*>(hp + i * 8);
            float4 w0 = *reinterpret_cast<const float4*>(wo + i * 8);
            float4 w1 = *reinterpret_cast<const float4*>(wo + i * 8 + 4);
            p += bf2f(hv[0]) * w0.x + bf2f(hv[1]) * w0.y + bf2f(hv[2]) * w0.z + bf2f(hv[3]) * w0.w
               + bf2f(hv[4]) * w1.x + bf2f(hv[5]) * w1.y + bf2f(hv[6]) * w1.z + bf2f(hv[7]) * w1.w;
        }
        p += __shfl_xor(p, 1); p += __shfl_xor(p, 2); p += __shfl_xor(p, 4);
        if (q == 0) out[gb * (Tx * OUTD) + j * OUTD + hs] = p + b_out[hs];
    }
    if (j >= Tx - 1) return;

    __shared__ __align__(16) char smem[2 * ROWS * KP * 2 + 1536];
    u16*   As   = (u16*)smem;
    u16*   Ws   = (u16*)(smem + ROWS * KP * 2);
    float* gbuf = (float*)smem;

    {
        const int r = tid >> 3, t8 = tid & 7;
        const int gb = bs * ROWS + r;
        const float* tg = target + (gb * Tx + j) * OUTD;
#pragma unroll
        for (int m = 0; m < 12; ++m) {
            const int k = t8 * 12 + m;
            float v;
            if (k < OUTD) v = (j == 0) ? 1.0f : tg[k];
            else          v = cond[gb * CND + (k - OUTD)];
            As[r * KP + k] = f2bf(v);
        }
    }
#pragma unroll
    for (int it = 0; it < 8; ++it) {
        const int rr = w + it * 4;
        gl_lds16(hprev + (bs * ROWS + rr) * HIDN + lane * 8, (void*)(As + rr * KP + 96));
    }
    {
        const u16* wsrc = Wg + hs * (NCOLS * KP);
#pragma unroll
        for (int it = 0; it < 10; ++it) {
            const int seg = it * 256 + w * 64;
            gl_lds16(wsrc + seg * 8 + lane * 8, (void*)(Ws + seg * 8));
        }
    }
    __syncthreads();

    const int mrow = ((w & 1) << 4) + (lane & 15);
    const int ncol = ((w >> 1) << 4) + (lane & 15);
    const int kq   = (lane >> 4) << 3;
    const u16* ap = As + mrow * KP + kq;
    const u16* bp = Ws + ncol * KP + kq;
    f32x4 acc = {0.f, 0.f, 0.f, 0.f};
#pragma unroll
    for (int ck = 0; ck < 19; ++ck) {
        s16x8 a = *reinterpret_cast<const s16x8*>(ap + ck * 32);
        s16x8 b = *reinterpret_cast<const s16x8*>(bp + ck * 32);
        acc = __builtin_amdgcn_mfma_f32_16x16x32_bf16(a, b, acc, 0, 0, 0);
    }
    __syncthreads();

    {
        const int row0 = ((w & 1) << 4) + ((lane >> 4) << 2);
#pragma unroll
        for (int t = 0; t < 4; ++t) gbuf[(row0 + t) * 36 + ncol] = acc[t];
    }
    __syncthreads();

    {
        const int r = tid >> 3, u = tid & 7;
        const int gb = bs * ROWS + r, hu = hs * 8 + u;
        const float gi = gbuf[r * 36 +      u] + bsum[0 * HIDN + hu];
        const float gf = gbuf[r * 36 +  8 + u] + bsum[1 * HIDN + hu];
        const float gg = gbuf[r * 36 + 16 + u] + bsum[2 * HIDN + hu];
        const float go = gbuf[r * 36 + 24 + u] + bsum[3 * HIDN + hu];
        const float ig = sigmoidf_(gi), fg = sigmoidf_(gf);
        const float gt = tanhf(gg),     og = sigmoidf_(go);
        const float co = cbuf[gb * HIDN + hu];
        const float cn = fg * co + ig * gt;
        cbuf[gb * HIDN + hu]  = cn;
        hnext[gb * HIDN + hu] = f2bf(og * tanhf(cn));
    }
}

// ---------------------------------------------------------------------------
extern "C" void kernel_launch(void* const* d_in, const int* in_sizes, int n_in,
                              void* d_out, int out_size, void* d_ws, size_t ws_size,
                              hipStream_t stream) {
    const float* latent = (const float*)d_in[0];
    const float* cond   = (const float*)d_in[1];
    const float* target = (const float*)d_in[2];
    const float* W_lh   = (const float*)d_in[3];
    const float* b_lh   = (const float*)d_in[4];
    const float* W_lc   = (const float*)d_in[5];
    const float* b_lc   = (const float*)d_in[6];
    const float* W_ih   = (const float*)d_in[7];
    const float* W_hh   = (const float*)d_in[8];
    const float* b_ih   = (const float*)d_in[9];
    const float* b_hh   = (const float*)d_in[10];
    const float* W_out  = (const float*)d_in[11];
    const float* b_out  = (const float*)d_in[12];

    float* out = (float*)d_out;
    char*  ws  = (char*)d_ws;
    u16*   Wg    = (u16*)(ws + WG_OFF);
    u16*   Wg2   = (u16*)(ws + WG2_OFF);
    u16*   hbuf0 = (u16*)(ws + H0_OFF);
    u16*   hbuf1 = (u16*)(ws + H1_OFF);
    float* cbuf  = (float*)(ws + CB_OFF);
    float* bsum  = (float*)(ws + BS_OFF);
    u32*   done  = (u32*)(ws + DN_OFF);

    hipLaunchKernelGGL(prep_w, dim3(4864), dim3(256), 0, stream,
                       W_ih, W_hh, b_ih, b_hh, Wg, Wg2, bsum, done);
    hipLaunchKernelGGL(init_kernel, dim3(Bx), dim3(256), 0, stream,
                       latent, W_lh, b_lh, W_lc, b_lc, hbuf0, cbuf, out);

    {
        // allow 128 KB dynamic LDS (ignore error; launch failure -> fallback)
        (void)hipFuncSetAttribute(reinterpret_cast<const void*>(persist_kernel),
                                  hipFuncAttributeMaxDynamicSharedMemorySize, PSMEM);
        const float* t_  = target;  const float* c_  = cond;
        u16*         h0_ = hbuf0;   u16*         h1_ = hbuf1;
        const float* cb_ = cbuf;    const u16*   wg_ = Wg;
        const float* bs_ = bsum;    const float* wo_ = W_out;
        const float* bo_ = b_out;   float*       o_  = out;
        u32*         dn_ = done;
        void* args[] = { &t_, &c_, &h0_, &h1_, &cb_, &wg_, &bs_, &wo_, &bo_, &o_, &dn_ };
        hipError_t err = hipLaunchCooperativeKernel(
            reinterpret_cast<const void*>(persist_kernel),
            dim3(256), dim3(256), args, PSMEM, stream);
        if (err != hipSuccess) {
            // fallback: verified per-step launch loop (old Wg2 layout)
            for (int j = 0; j < Tx; ++j) {
                u16* hp = (j & 1) ? hbuf1 : hbuf0;
                u16* hn = (j & 1) ? hbuf0 : hbuf1;
                hipLaunchKernelGGL(step_kernel, dim3(512), dim3(256), 0, stream,
                                   j, target, cond, hp, hn, cbuf,
                                   Wg2, bsum, W_out, b_out, out);
            }
        }
    }
}